// Round 2
// baseline (358.357 us; speedup 1.0000x reference)
//
#include <hip/hip_runtime.h>

#define NB   8
#define TSRC 4096
#define TTGT 2048
#define CH   1024   // C_IN == C_OUT
#define BK   64

typedef __attribute__((ext_vector_type(4))) float  f32x4;
typedef __attribute__((ext_vector_type(8))) __bf16 bf16x8;
typedef __attribute__((ext_vector_type(4))) __bf16 bf16x4;

__device__ __forceinline__ void async16(const void* g, void* l) {
  __builtin_amdgcn_global_load_lds((const __attribute__((address_space(1))) void*)g,
                                   (__attribute__((address_space(3))) void*)l, 16, 0, 0);
}

// ---- kernel 1: prep = W f32->bf16 + ragged sizes + mask passthrough ---------------
// grid: [0, 1024)      W row convert
//       [1024, 1040)   sizes: src_sizes -> sizes[0..7], tgt_sizes -> sizes[8..15]
//       [1040, 1168)   mask passthrough (32768 ints -> f32)
__global__ __launch_bounds__(256) void prep_kernel(const float* __restrict__ W,
                                                   const int* __restrict__ src_mask,
                                                   const int* __restrict__ tgt_mask,
                                                   __bf16* __restrict__ Wbf,
                                                   int* __restrict__ sizes,
                                                   float* __restrict__ mask_out) {
  const int bx = blockIdx.x;
  const int t  = threadIdx.x;
  if (bx < CH) {
    const float4 v = ((const float4*)(W + (size_t)bx * CH))[t];
    bf16x4 u = {(__bf16)v.x, (__bf16)v.y, (__bf16)v.z, (__bf16)v.w};
    *(bf16x4*)(Wbf + (size_t)bx * CH + t * 4) = u;
  } else if (bx < CH + 16) {
    const int id = bx - CH;                  // 0..7 src, 8..15 tgt
    const int b  = id & 7;
    const int* m = (id < 8) ? (src_mask + (size_t)b * TSRC) : (tgt_mask + (size_t)b * TTGT);
    const int T  = (id < 8) ? TSRC : TTGT;
    int s = 0;
    for (int i = t; i < T; i += 256) s += m[i];
#pragma unroll
    for (int off = 32; off > 0; off >>= 1) s += __shfl_down(s, off);
    __shared__ int red[4];
    if ((t & 63) == 0) red[t >> 6] = s;
    __syncthreads();
    if (t == 0) sizes[id] = red[0] + red[1] + red[2] + red[3];
  } else {
    const int i = (bx - (CH + 16)) * 256 + t;
    mask_out[i] = (float)src_mask[i];
  }
}

// ---- kernel 2: y = A @ W^T + bias; A stays f32 in LDS, cvt fused at fragment load --
// A [M=NB*TTGT, K=CH] f32 row-major (tgt, read directly — no prep round-trip);
// Wbf [N=CH, K=CH] bf16 row-major (NT GEMM). 128x128 tile, BK=64, 4 waves 2x2.
// Sync schedule identical to the proven round-0 kernel: ALL staging goes through
// global_load_lds issued together at loop top, ONE drain point per K-step
// (__syncthreads after issue), compute, barrier. As holds raw f32 (32 KB) —
// global_load_lds is type-agnostic; the f32->bf16 convert happens per-fragment
// after ds_read (2x ds_read_b128 + packed cvt), overlapped with MFMA across waves.
// LDS 48 KB -> 3 blocks/CU (grid gives ~4/CU with ~23% early-exit => ~3 resident).
// Swizzle: bid%8 == Mt%8 -> all 8 N-blocks of one M-tile land on the same XCD.
__global__ __launch_bounds__(256) void gemm_kernel(const float* __restrict__ A32,
                                                   const __bf16* __restrict__ Bw,
                                                   const float* __restrict__ bias,
                                                   const int* __restrict__ sizes,
                                                   __bf16* __restrict__ y) {
  const int bid = blockIdx.x;        // 0..1023
  const int Mt  = bid & 127;         // m-tile (bid%8 == Mt%8 -> XCD affinity)
  const int Nt  = bid >> 7;          // 0..7
  const int n0 = Nt * 128;
  const int m0 = Mt * 128;
  const int b  = m0 >> 11;
  const int t0 = m0 & (TTGT - 1);
  if (t0 >= sizes[8 + b]) return;    // rows never gathered

  __shared__ float  As[128 * BK];    // f32, 32 KB
  __shared__ __bf16 Bs[128 * BK];    // bf16, 16 KB

  const int tid  = threadIdx.x;
  const int lane = tid & 63;
  const int wave = tid >> 6;
  const int wm   = (wave >> 1) * 64;
  const int wn   = (wave & 1) * 64;
  const int lr   = lane & 15;
  const int quad = lane >> 4;

  // A staging: issue q covers rows [q*16, q*16+16); thread t -> row q*16 + t/16,
  //            f32 col (t%16)*4; LDS f32-elem offset q*1024 + tid*4 (linear, 16B/lane)
  const int arow = tid >> 4;
  const int acol = (tid & 15) * 4;
  const float* gA = A32 + (size_t)(m0 + arow) * CH + acol;
  float* lA = As + tid * 4;
  // B staging: issue q covers rows [q*32, q*32+32); thread t -> row q*32 + t/8,
  //            bf16 col (t%8)*8; LDS elem offset q*2048 + tid*8
  const int brow = tid >> 3;
  const int bcol = (tid & 7) * 8;
  const __bf16* gB = Bw + (size_t)(n0 + brow) * CH + bcol;
  __bf16* lB = Bs + tid * 8;

  f32x4 acc[4][4];
  const f32x4 z = {0.f, 0.f, 0.f, 0.f};
#pragma unroll
  for (int i = 0; i < 4; ++i)
#pragma unroll
    for (int j = 0; j < 4; ++j) acc[i][j] = z;

  for (int kb = 0; kb < CH; kb += BK) {
#pragma unroll
    for (int q = 0; q < 8; ++q)
      async16(gA + (size_t)q * 16 * CH + kb, lA + q * 1024);
#pragma unroll
    for (int q = 0; q < 4; ++q)
      async16(gB + (size_t)q * 32 * CH + kb, lB + q * 2048);
    __syncthreads();               // single drain point per K-step (round-0 schedule)
#pragma unroll
    for (int ko = 0; ko < 2; ++ko) {
      bf16x8 af[4], bf[4];
#pragma unroll
      for (int i = 0; i < 4; ++i) {
        const float* ap = As + (wm + i * 16 + lr) * BK + ko * 32 + quad * 8;
        const f32x4 v0 = *(const f32x4*)ap;
        const f32x4 v1 = *(const f32x4*)(ap + 4);
        bf16x8 a;
#pragma unroll
        for (int k = 0; k < 4; ++k) { a[k] = (__bf16)v0[k]; a[4 + k] = (__bf16)v1[k]; }
        af[i] = a;
      }
#pragma unroll
      for (int j = 0; j < 4; ++j)
        bf[j] = *(const bf16x8*)(Bs + (wn + j * 16 + lr) * BK + ko * 32 + quad * 8);
#pragma unroll
      for (int i = 0; i < 4; ++i)
#pragma unroll
        for (int j = 0; j < 4; ++j)
          acc[i][j] = __builtin_amdgcn_mfma_f32_16x16x32_bf16(af[i], bf[j], acc[i][j], 0, 0, 0);
    }
    __syncthreads();
  }

  // epilogue: C/D layout col = lane&15, row = quad*4 + reg; store bf16
#pragma unroll
  for (int i = 0; i < 4; ++i) {
    const int mrow = m0 + wm + i * 16 + quad * 4;
#pragma unroll
    for (int j = 0; j < 4; ++j) {
      const int ncol = n0 + wn + j * 16 + lr;
      const float bv = bias[ncol];
      __bf16* yp = y + (size_t)mrow * CH + ncol;
#pragma unroll
      for (int r = 0; r < 4; ++r) yp[(size_t)r * CH] = (__bf16)(acc[i][j][r] + bv);
    }
  }
}

// ---- kernel 3: gather + LayerNorm, wave-per-row (no barriers) ----------------------
__global__ __launch_bounds__(256) void ln_kernel(const __bf16* __restrict__ y,
                                                 const int* __restrict__ sizes,
                                                 const float* __restrict__ g,
                                                 const float* __restrict__ be,
                                                 float* __restrict__ out) {
  const int wid = (blockIdx.x * 256 + threadIdx.x) >> 6;  // 0..8191
  const int l   = threadIdx.x & 63;
#pragma unroll
  for (int rr = 0; rr < 4; ++rr) {
    const int row = wid + rr * 8192;        // 0..32767
    const int b   = row >> 12;
    const int j   = row & (TSRC - 1);
    const int ss  = sizes[b];
    const int tg  = sizes[8 + b];
    float v[16];
    if (j < ss) {
      const int den = (ss > 0) ? ss : 1;
      int ii = (int)(((long long)j * (long long)tg) / den);
      const int hi = ((tg > 1) ? tg : 1) - 1;
      ii = (ii > hi) ? hi : ((ii < 0) ? 0 : ii);
      const __bf16* yr = y + ((size_t)b * TTGT + ii) * CH;
      const bf16x8 u0 = *(const bf16x8*)(yr + l * 8);
      const bf16x8 u1 = *(const bf16x8*)(yr + 512 + l * 8);
#pragma unroll
      for (int k = 0; k < 8; ++k) { v[k] = (float)u0[k]; v[8 + k] = (float)u1[k]; }
    } else {
#pragma unroll
      for (int k = 0; k < 16; ++k) v[k] = 0.f;
    }
    float s = 0.f, q = 0.f;
#pragma unroll
    for (int k = 0; k < 16; ++k) { s += v[k]; q += v[k] * v[k]; }
#pragma unroll
    for (int off = 32; off > 0; off >>= 1) {
      s += __shfl_xor(s, off);
      q += __shfl_xor(q, off);
    }
    const float mu = s * (1.0f / CH);
    float var = q * (1.0f / CH) - mu * mu;
    var = fmaxf(var, 0.0f);
    const float rs = rsqrtf(var + 1e-5f);
    float* orow = out + (size_t)row * CH;
#pragma unroll
    for (int h = 0; h < 2; ++h) {
      const int base = h * 512 + l * 8;
      const float4 g0 = *(const float4*)(g + base);
      const float4 g1 = *(const float4*)(g + base + 4);
      const float4 b0 = *(const float4*)(be + base);
      const float4 b1 = *(const float4*)(be + base + 4);
      float4 o0, o1;
      o0.x = (v[h * 8 + 0] - mu) * rs * g0.x + b0.x;
      o0.y = (v[h * 8 + 1] - mu) * rs * g0.y + b0.y;
      o0.z = (v[h * 8 + 2] - mu) * rs * g0.z + b0.z;
      o0.w = (v[h * 8 + 3] - mu) * rs * g0.w + b0.w;
      o1.x = (v[h * 8 + 4] - mu) * rs * g1.x + b1.x;
      o1.y = (v[h * 8 + 5] - mu) * rs * g1.y + b1.y;
      o1.z = (v[h * 8 + 6] - mu) * rs * g1.z + b1.z;
      o1.w = (v[h * 8 + 7] - mu) * rs * g1.w + b1.w;
      *(float4*)(orow + base)     = o0;
      *(float4*)(orow + base + 4) = o1;
    }
  }
}

// ---------------- fallback: fully self-contained, no workspace needed ---------------
__global__ __launch_bounds__(256) void fallback_kernel(const float* __restrict__ tgt,
                                                       const int* __restrict__ src_mask,
                                                       const int* __restrict__ tgt_mask,
                                                       const float* __restrict__ W,
                                                       const float* __restrict__ bias,
                                                       const float* __restrict__ g,
                                                       const float* __restrict__ be,
                                                       float* __restrict__ out,
                                                       float* __restrict__ mask_out) {
  const int bx = blockIdx.x;
  const int b  = bx >> 12;
  const int j  = bx & (TSRC - 1);
  const int t  = threadIdx.x;
  int s1 = 0, s2 = 0;
  for (int i = t; i < TSRC; i += 256) s1 += src_mask[(size_t)b * TSRC + i];
  for (int i = t; i < TTGT; i += 256) s2 += tgt_mask[(size_t)b * TTGT + i];
#pragma unroll
  for (int off = 32; off > 0; off >>= 1) { s1 += __shfl_down(s1, off); s2 += __shfl_down(s2, off); }
  __shared__ int ired[8];
  if ((t & 63) == 0) { ired[t >> 6] = s1; ired[4 + (t >> 6)] = s2; }
  __syncthreads();
  const int ss = ired[0] + ired[1] + ired[2] + ired[3];
  const int tg = ired[4] + ired[5] + ired[6] + ired[7];
  const bool valid = j < ss;
  int ii = 0;
  if (valid) {
    const int den = (ss > 0) ? ss : 1;
    ii = (int)(((long long)j * (long long)tg) / den);
    const int hi = ((tg > 1) ? tg : 1) - 1;
    if (ii > hi) ii = hi;
    if (ii < 0) ii = 0;
  }
  __shared__ float trow[CH];
  const float* tr = tgt + ((size_t)b * TTGT + ii) * CH;
  for (int i = t; i < CH; i += 256) trow[i] = valid ? tr[i] : 0.0f;
  __syncthreads();
  float4 v = make_float4(0.f, 0.f, 0.f, 0.f);
  if (valid) {
    float a0 = 0.f, a1 = 0.f, a2 = 0.f, a3 = 0.f;
    const float* w0 = W + (size_t)(4 * t + 0) * CH;
    const float* w1 = W + (size_t)(4 * t + 1) * CH;
    const float* w2 = W + (size_t)(4 * t + 2) * CH;
    const float* w3 = W + (size_t)(4 * t + 3) * CH;
    for (int k = 0; k < CH; ++k) {
      const float x = trow[k];
      a0 += x * w0[k]; a1 += x * w1[k]; a2 += x * w2[k]; a3 += x * w3[k];
    }
    v.x = a0 + bias[4 * t + 0];
    v.y = a1 + bias[4 * t + 1];
    v.z = a2 + bias[4 * t + 2];
    v.w = a3 + bias[4 * t + 3];
  }
  float s  = v.x + v.y + v.z + v.w;
  float sq = v.x * v.x + v.y * v.y + v.z * v.z + v.w * v.w;
#pragma unroll
  for (int off = 32; off > 0; off >>= 1) {
    s  += __shfl_down(s, off);
    sq += __shfl_down(sq, off);
  }
  __shared__ float red[8];
  __shared__ float stats[2];
  if ((t & 63) == 0) { red[t >> 6] = s; red[4 + (t >> 6)] = sq; }
  __syncthreads();
  if (t == 0) {
    const float S  = red[0] + red[1] + red[2] + red[3];
    const float Q  = red[4] + red[5] + red[6] + red[7];
    const float mu = S * (1.0f / CH);
    float var = Q * (1.0f / CH) - mu * mu;
    var = fmaxf(var, 0.0f);
    stats[0] = mu;
    stats[1] = rsqrtf(var + 1e-5f);
  }
  __syncthreads();
  const float mu = stats[0], rs = stats[1];
  const float4 gg = ((const float4*)g)[t];
  const float4 bb = ((const float4*)be)[t];
  float4 o;
  o.x = (v.x - mu) * rs * gg.x + bb.x;
  o.y = (v.y - mu) * rs * gg.y + bb.y;
  o.z = (v.z - mu) * rs * gg.z + bb.z;
  o.w = (v.w - mu) * rs * gg.w + bb.w;
  ((float4*)(out + ((size_t)b * TSRC + j) * CH))[t] = o;
  if (t == 0) mask_out[bx] = (float)src_mask[bx];
}

extern "C" void kernel_launch(void* const* d_in, const int* in_sizes, int n_in,
                              void* d_out, int out_size, void* d_ws, size_t ws_size,
                              hipStream_t stream) {
  (void)in_sizes; (void)n_in; (void)out_size;
  // setup_inputs order: src, src_mask, tgt, tgt_mask, conv_w, conv_b, ln_g, ln_b
  const int*   src_mask = (const int*)d_in[1];
  const float* tgt      = (const float*)d_in[2];
  const int*   tgt_mask = (const int*)d_in[3];
  const float* conv_w   = (const float*)d_in[4];
  const float* conv_b   = (const float*)d_in[5];
  const float* ln_g     = (const float*)d_in[6];
  const float* ln_b     = (const float*)d_in[7];

  float* out      = (float*)d_out;
  float* mask_out = out + (size_t)NB * TSRC * CH;   // second tuple element, as f32

  const size_t M       = (size_t)NB * TTGT;              // 16384 rows
  const size_t off_wbf = 256;
  const size_t off_y   = off_wbf + (size_t)CH * CH * 2;  // +2 MiB
  const size_t need    = off_y + M * CH * 2;             // +32 MiB => ~34 MiB

  if (ws_size >= need) {
    int*    sizes = (int*)d_ws;
    __bf16* Wbf   = (__bf16*)((char*)d_ws + off_wbf);
    __bf16* y     = (__bf16*)((char*)d_ws + off_y);
    prep_kernel<<<CH + 16 + 128, 256, 0, stream>>>(conv_w, src_mask, tgt_mask,
                                                   Wbf, sizes, mask_out);
    gemm_kernel<<<1024, 256, 0, stream>>>(tgt, Wbf, conv_b, sizes, y);
    ln_kernel<<<2048, 256, 0, stream>>>(y, sizes, ln_g, ln_b, out);
  } else {
    fallback_kernel<<<NB * TSRC, 256, 0, stream>>>(tgt, src_mask, tgt_mask, conv_w, conv_b,
                                                   ln_g, ln_b, out, mask_out);
  }
}

// Round 4
// 350.740 us; speedup vs baseline: 1.0217x; 1.0217x over previous
//
#include <hip/hip_runtime.h>

#define NB   8
#define TSRC 4096
#define TTGT 2048
#define CH   1024   // C_IN == C_OUT
#define BK   64

typedef __attribute__((ext_vector_type(4))) float  f32x4;
typedef __attribute__((ext_vector_type(8))) __bf16 bf16x8;
typedef __attribute__((ext_vector_type(4))) __bf16 bf16x4;

__device__ __forceinline__ void async16(const void* g, void* l) {
  __builtin_amdgcn_global_load_lds((const __attribute__((address_space(1))) void*)g,
                                   (__attribute__((address_space(3))) void*)l, 16, 0, 0);
}

// ---- kernel 1: fused prep = f32->bf16 convert (tgt + W) + ragged sizes + mask out --
// (round-0 proven version, restored verbatim)
// grid: [0, 17408)   convert one row per block (tgt rows then W rows)
//       [17408,17424) sizes: src_sizes -> sizes[0..7], tgt_sizes -> sizes[8..15]
//       [17424,17552) mask passthrough (32768 ints -> f32)
__global__ __launch_bounds__(256) void prep_kernel(const float* __restrict__ tgt,
                                                   const float* __restrict__ W,
                                                   const int* __restrict__ src_mask,
                                                   const int* __restrict__ tgt_mask,
                                                   __bf16* __restrict__ Abf,
                                                   __bf16* __restrict__ Wbf,
                                                   int* __restrict__ sizes,
                                                   float* __restrict__ mask_out) {
  const int bx = blockIdx.x;
  const int t  = threadIdx.x;
  const int NCONV = NB * TTGT + CH;          // 17408
  if (bx < NCONV) {
    const float* sp;
    __bf16* dp;
    if (bx < NB * TTGT) { sp = tgt + (size_t)bx * CH; dp = Abf + (size_t)bx * CH; }
    else { const int r = bx - NB * TTGT; sp = W + (size_t)r * CH; dp = Wbf + (size_t)r * CH; }
    const float4 v = ((const float4*)sp)[t];
    bf16x4 u = {(__bf16)v.x, (__bf16)v.y, (__bf16)v.z, (__bf16)v.w};
    *(bf16x4*)(dp + t * 4) = u;
  } else if (bx < NCONV + 16) {
    const int id = bx - NCONV;               // 0..7 src, 8..15 tgt
    const int b  = id & 7;
    const int* m = (id < 8) ? (src_mask + (size_t)b * TSRC) : (tgt_mask + (size_t)b * TTGT);
    const int T  = (id < 8) ? TSRC : TTGT;
    int s = 0;
    for (int i = t; i < T; i += 256) s += m[i];
#pragma unroll
    for (int off = 32; off > 0; off >>= 1) s += __shfl_down(s, off);
    __shared__ int red[4];
    if ((t & 63) == 0) red[t >> 6] = s;
    __syncthreads();
    if (t == 0) sizes[id] = red[0] + red[1] + red[2] + red[3];
  } else {
    const int i = (bx - (NCONV + 16)) * 256 + t;
    mask_out[i] = (float)src_mask[i];
  }
}

// ---- kernel 2: y = A @ W^T + bias, bf16 in/out, m97-style, XCD-swizzled grid -------
// (round-0 proven version, restored verbatim)
__global__ __launch_bounds__(256) void gemm_kernel(const __bf16* __restrict__ A,
                                                   const __bf16* __restrict__ Bw,
                                                   const float* __restrict__ bias,
                                                   const int* __restrict__ sizes,
                                                   __bf16* __restrict__ y) {
  const int bid = blockIdx.x;        // 0..1023
  const int Mt  = bid & 127;         // m-tile (bid%8 == Mt%8 -> XCD affinity)
  const int Nt  = bid >> 7;          // 0..7
  const int n0 = Nt * 128;
  const int m0 = Mt * 128;
  const int b  = m0 >> 11;
  const int t0 = m0 & (TTGT - 1);
  if (t0 >= sizes[8 + b]) return;    // rows never gathered

  __shared__ __bf16 As[128 * BK];    // 16 KB
  __shared__ __bf16 Bs[128 * BK];    // 16 KB

  const int tid  = threadIdx.x;
  const int lane = tid & 63;
  const int wave = tid >> 6;
  const int wm   = (wave >> 1) * 64;
  const int wn   = (wave & 1) * 64;
  const int lr   = lane & 15;
  const int quad = lane >> 4;

  // staging: thread t, issue q -> LDS elem q*2048 + t*8 (= row (q*32 + t/8), col (t%8)*8)
  const int srow = tid >> 3;
  const int scol = (tid & 7) * 8;
  const __bf16* gA = A  + ((size_t)(m0 + srow)) * CH + scol;
  const __bf16* gB = Bw + ((size_t)(n0 + srow)) * CH + scol;
  __bf16* lA = As + tid * 8;
  __bf16* lB = Bs + tid * 8;

  f32x4 acc[4][4];
  const f32x4 z = {0.f, 0.f, 0.f, 0.f};
#pragma unroll
  for (int i = 0; i < 4; ++i)
#pragma unroll
    for (int j = 0; j < 4; ++j) acc[i][j] = z;

  for (int kb = 0; kb < CH; kb += BK) {
#pragma unroll
    for (int q = 0; q < 4; ++q) {
      async16(gA + (size_t)q * 32 * CH + kb, lA + q * 2048);
      async16(gB + (size_t)q * 32 * CH + kb, lB + q * 2048);
    }
    __syncthreads();
#pragma unroll
    for (int ko = 0; ko < 2; ++ko) {
      bf16x8 af[4], bf[4];
#pragma unroll
      for (int i = 0; i < 4; ++i)
        af[i] = *(const bf16x8*)(As + (wm + i * 16 + lr) * BK + ko * 32 + quad * 8);
#pragma unroll
      for (int j = 0; j < 4; ++j)
        bf[j] = *(const bf16x8*)(Bs + (wn + j * 16 + lr) * BK + ko * 32 + quad * 8);
#pragma unroll
      for (int i = 0; i < 4; ++i)
#pragma unroll
        for (int j = 0; j < 4; ++j)
          acc[i][j] = __builtin_amdgcn_mfma_f32_16x16x32_bf16(af[i], bf[j], acc[i][j], 0, 0, 0);
    }
    __syncthreads();
  }

  // epilogue: C/D layout col = lane&15, row = quad*4 + reg; store bf16
#pragma unroll
  for (int i = 0; i < 4; ++i) {
    const int mrow = m0 + wm + i * 16 + quad * 4;
#pragma unroll
    for (int j = 0; j < 4; ++j) {
      const int ncol = n0 + wn + j * 16 + lr;
      const float bv = bias[ncol];
      __bf16* yp = y + (size_t)mrow * CH + ncol;
#pragma unroll
      for (int r = 0; r < 4; ++r) yp[(size_t)r * CH] = (__bf16)(acc[i][j][r] + bv);
    }
  }
}

// ---- kernel 3: gather + LayerNorm, wave-per-row (no barriers) ----------------------
// Round-4 changes vs the proven version:
//  (a) nontemporal stores for `out` (134 MB f32, never re-read by GPU) — stream past
//      L2 instead of write-allocating into the 4 MiB/XCD L2 alongside y-gather reads.
//      Uses ext-vector f32x4 (clang builtin requires scalar/ext-vector, not float4).
//  (b) gamma/beta hoisted into registers once per wave (was 16 float4 loads per ROW).
// Everything else (grid, gather math, reductions) identical.
__global__ __launch_bounds__(256) void ln_kernel(const __bf16* __restrict__ y,
                                                 const int* __restrict__ sizes,
                                                 const float* __restrict__ g,
                                                 const float* __restrict__ be,
                                                 float* __restrict__ out) {
  const int wid = (blockIdx.x * 256 + threadIdx.x) >> 6;  // 0..8191
  const int l   = threadIdx.x & 63;

  // hoist gamma/beta: this wave always touches the same 16 channels per lane
  float gr[16], br[16];
#pragma unroll
  for (int h = 0; h < 2; ++h) {
    const int base = h * 512 + l * 8;
    *(f32x4*)(gr + h * 8)     = *(const f32x4*)(g + base);
    *(f32x4*)(gr + h * 8 + 4) = *(const f32x4*)(g + base + 4);
    *(f32x4*)(br + h * 8)     = *(const f32x4*)(be + base);
    *(f32x4*)(br + h * 8 + 4) = *(const f32x4*)(be + base + 4);
  }

#pragma unroll
  for (int rr = 0; rr < 4; ++rr) {
    const int row = wid + rr * 8192;        // 0..32767
    const int b   = row >> 12;
    const int j   = row & (TSRC - 1);
    const int ss  = sizes[b];
    const int tg  = sizes[8 + b];
    float v[16];
    if (j < ss) {
      const int den = (ss > 0) ? ss : 1;
      int ii = (int)(((long long)j * (long long)tg) / den);
      const int hi = ((tg > 1) ? tg : 1) - 1;
      ii = (ii > hi) ? hi : ((ii < 0) ? 0 : ii);
      const __bf16* yr = y + ((size_t)b * TTGT + ii) * CH;
      const bf16x8 u0 = *(const bf16x8*)(yr + l * 8);
      const bf16x8 u1 = *(const bf16x8*)(yr + 512 + l * 8);
#pragma unroll
      for (int k = 0; k < 8; ++k) { v[k] = (float)u0[k]; v[8 + k] = (float)u1[k]; }
    } else {
#pragma unroll
      for (int k = 0; k < 16; ++k) v[k] = 0.f;
    }
    float s = 0.f, q = 0.f;
#pragma unroll
    for (int k = 0; k < 16; ++k) { s += v[k]; q += v[k] * v[k]; }
#pragma unroll
    for (int off = 32; off > 0; off >>= 1) {
      s += __shfl_xor(s, off);
      q += __shfl_xor(q, off);
    }
    const float mu = s * (1.0f / CH);
    float var = q * (1.0f / CH) - mu * mu;
    var = fmaxf(var, 0.0f);
    const float rs = rsqrtf(var + 1e-5f);
    float* orow = out + (size_t)row * CH;
#pragma unroll
    for (int h = 0; h < 2; ++h) {
      const int base = h * 512 + l * 8;
      f32x4 o0, o1;
      o0[0] = (v[h * 8 + 0] - mu) * rs * gr[h * 8 + 0] + br[h * 8 + 0];
      o0[1] = (v[h * 8 + 1] - mu) * rs * gr[h * 8 + 1] + br[h * 8 + 1];
      o0[2] = (v[h * 8 + 2] - mu) * rs * gr[h * 8 + 2] + br[h * 8 + 2];
      o0[3] = (v[h * 8 + 3] - mu) * rs * gr[h * 8 + 3] + br[h * 8 + 3];
      o1[0] = (v[h * 8 + 4] - mu) * rs * gr[h * 8 + 4] + br[h * 8 + 4];
      o1[1] = (v[h * 8 + 5] - mu) * rs * gr[h * 8 + 5] + br[h * 8 + 5];
      o1[2] = (v[h * 8 + 6] - mu) * rs * gr[h * 8 + 6] + br[h * 8 + 6];
      o1[3] = (v[h * 8 + 7] - mu) * rs * gr[h * 8 + 7] + br[h * 8 + 7];
      __builtin_nontemporal_store(o0, (f32x4*)(orow + base));
      __builtin_nontemporal_store(o1, (f32x4*)(orow + base + 4));
    }
  }
}

// ---------------- fallback: fully self-contained, no workspace needed ---------------
__global__ __launch_bounds__(256) void fallback_kernel(const float* __restrict__ tgt,
                                                       const int* __restrict__ src_mask,
                                                       const int* __restrict__ tgt_mask,
                                                       const float* __restrict__ W,
                                                       const float* __restrict__ bias,
                                                       const float* __restrict__ g,
                                                       const float* __restrict__ be,
                                                       float* __restrict__ out,
                                                       float* __restrict__ mask_out) {
  const int bx = blockIdx.x;
  const int b  = bx >> 12;
  const int j  = bx & (TSRC - 1);
  const int t  = threadIdx.x;
  int s1 = 0, s2 = 0;
  for (int i = t; i < TSRC; i += 256) s1 += src_mask[(size_t)b * TSRC + i];
  for (int i = t; i < TTGT; i += 256) s2 += tgt_mask[(size_t)b * TTGT + i];
#pragma unroll
  for (int off = 32; off > 0; off >>= 1) { s1 += __shfl_down(s1, off); s2 += __shfl_down(s2, off); }
  __shared__ int ired[8];
  if ((t & 63) == 0) { ired[t >> 6] = s1; ired[4 + (t >> 6)] = s2; }
  __syncthreads();
  const int ss = ired[0] + ired[1] + ired[2] + ired[3];
  const int tg = ired[4] + ired[5] + ired[6] + ired[7];
  const bool valid = j < ss;
  int ii = 0;
  if (valid) {
    const int den = (ss > 0) ? ss : 1;
    ii = (int)(((long long)j * (long long)tg) / den);
    const int hi = ((tg > 1) ? tg : 1) - 1;
    if (ii > hi) ii = hi;
    if (ii < 0) ii = 0;
  }
  __shared__ float trow[CH];
  const float* tr = tgt + ((size_t)b * TTGT + ii) * CH;
  for (int i = t; i < CH; i += 256) trow[i] = valid ? tr[i] : 0.0f;
  __syncthreads();
  float4 v = make_float4(0.f, 0.f, 0.f, 0.f);
  if (valid) {
    float a0 = 0.f, a1 = 0.f, a2 = 0.f, a3 = 0.f;
    const float* w0 = W + (size_t)(4 * t + 0) * CH;
    const float* w1 = W + (size_t)(4 * t + 1) * CH;
    const float* w2 = W + (size_t)(4 * t + 2) * CH;
    const float* w3 = W + (size_t)(4 * t + 3) * CH;
    for (int k = 0; k < CH; ++k) {
      const float x = trow[k];
      a0 += x * w0[k]; a1 += x * w1[k]; a2 += x * w2[k]; a3 += x * w3[k];
    }
    v.x = a0 + bias[4 * t + 0];
    v.y = a1 + bias[4 * t + 1];
    v.z = a2 + bias[4 * t + 2];
    v.w = a3 + bias[4 * t + 3];
  }
  float s  = v.x + v.y + v.z + v.w;
  float sq = v.x * v.x + v.y * v.y + v.z * v.z + v.w * v.w;
#pragma unroll
  for (int off = 32; off > 0; off >>= 1) {
    s  += __shfl_down(s, off);
    sq += __shfl_down(sq, off);
  }
  __shared__ float red[8];
  __shared__ float stats[2];
  if ((t & 63) == 0) { red[t >> 6] = s; red[4 + (t >> 6)] = sq; }
  __syncthreads();
  if (t == 0) {
    const float S  = red[0] + red[1] + red[2] + red[3];
    const float Q  = red[4] + red[5] + red[6] + red[7];
    const float mu = S * (1.0f / CH);
    float var = Q * (1.0f / CH) - mu * mu;
    var = fmaxf(var, 0.0f);
    stats[0] = mu;
    stats[1] = rsqrtf(var + 1e-5f);
  }
  __syncthreads();
  const float mu = stats[0], rs = stats[1];
  const float4 gg = ((const float4*)g)[t];
  const float4 bb = ((const float4*)be)[t];
  float4 o;
  o.x = (v.x - mu) * rs * gg.x + bb.x;
  o.y = (v.y - mu) * rs * gg.y + bb.y;
  o.z = (v.z - mu) * rs * gg.z + bb.z;
  o.w = (v.w - mu) * rs * gg.w + bb.w;
  ((float4*)(out + ((size_t)b * TSRC + j) * CH))[t] = o;
  if (t == 0) mask_out[bx] = (float)src_mask[bx];
}

extern "C" void kernel_launch(void* const* d_in, const int* in_sizes, int n_in,
                              void* d_out, int out_size, void* d_ws, size_t ws_size,
                              hipStream_t stream) {
  (void)in_sizes; (void)n_in; (void)out_size;
  // setup_inputs order: src, src_mask, tgt, tgt_mask, conv_w, conv_b, ln_g, ln_b
  const int*   src_mask = (const int*)d_in[1];
  const float* tgt      = (const float*)d_in[2];
  const int*   tgt_mask = (const int*)d_in[3];
  const float* conv_w   = (const float*)d_in[4];
  const float* conv_b   = (const float*)d_in[5];
  const float* ln_g     = (const float*)d_in[6];
  const float* ln_b     = (const float*)d_in[7];

  float* out      = (float*)d_out;
  float* mask_out = out + (size_t)NB * TSRC * CH;   // second tuple element, as f32

  const size_t M       = (size_t)NB * TTGT;              // 16384 rows
  const size_t off_abf = 256;
  const size_t off_wbf = off_abf + M * CH * 2;           // +32 MiB
  const size_t off_y   = off_wbf + (size_t)CH * CH * 2;  // +2 MiB
  const size_t need    = off_y + M * CH * 2;             // +32 MiB => ~66 MiB

  if (ws_size >= need) {
    int*    sizes = (int*)d_ws;
    __bf16* Abf   = (__bf16*)((char*)d_ws + off_abf);
    __bf16* Wbf   = (__bf16*)((char*)d_ws + off_wbf);
    __bf16* y     = (__bf16*)((char*)d_ws + off_y);
    prep_kernel<<<NB * TTGT + CH + 16 + 128, 256, 0, stream>>>(tgt, conv_w, src_mask, tgt_mask,
                                                               Abf, Wbf, sizes, mask_out);
    gemm_kernel<<<1024, 256, 0, stream>>>(Abf, Wbf, conv_b, sizes, y);
    ln_kernel<<<2048, 256, 0, stream>>>(y, sizes, ln_g, ln_b, out);
  } else {
    fallback_kernel<<<NB * TSRC, 256, 0, stream>>>(tgt, src_mask, tgt_mask, conv_w, conv_b,
                                                   ln_g, ln_b, out, mask_out);
  }
}

// Round 5
// 306.322 us; speedup vs baseline: 1.1699x; 1.1450x over previous
//
#include <hip/hip_runtime.h>

#define NB   8
#define TSRC 4096
#define TTGT 2048
#define CH   1024   // C_IN == C_OUT
#define BK   64

typedef __attribute__((ext_vector_type(4))) float  f32x4;
typedef __attribute__((ext_vector_type(8))) __bf16 bf16x8;
typedef __attribute__((ext_vector_type(4))) __bf16 bf16x4;

__device__ __forceinline__ void async16(const void* g, void* l) {
  __builtin_amdgcn_global_load_lds((const __attribute__((address_space(1))) void*)g,
                                   (__attribute__((address_space(3))) void*)l, 16, 0, 0);
}

// ---- kernel 1: fused prep = f32->bf16 convert (tgt + W) + ragged sizes + mask out --
// (round-0 proven version)
__global__ __launch_bounds__(256) void prep_kernel(const float* __restrict__ tgt,
                                                   const float* __restrict__ W,
                                                   const int* __restrict__ src_mask,
                                                   const int* __restrict__ tgt_mask,
                                                   __bf16* __restrict__ Abf,
                                                   __bf16* __restrict__ Wbf,
                                                   int* __restrict__ sizes,
                                                   float* __restrict__ mask_out) {
  const int bx = blockIdx.x;
  const int t  = threadIdx.x;
  const int NCONV = NB * TTGT + CH;          // 17408
  if (bx < NCONV) {
    const float* sp;
    __bf16* dp;
    if (bx < NB * TTGT) { sp = tgt + (size_t)bx * CH; dp = Abf + (size_t)bx * CH; }
    else { const int r = bx - NB * TTGT; sp = W + (size_t)r * CH; dp = Wbf + (size_t)r * CH; }
    const float4 v = ((const float4*)sp)[t];
    bf16x4 u = {(__bf16)v.x, (__bf16)v.y, (__bf16)v.z, (__bf16)v.w};
    *(bf16x4*)(dp + t * 4) = u;
  } else if (bx < NCONV + 16) {
    const int id = bx - NCONV;               // 0..7 src, 8..15 tgt
    const int b  = id & 7;
    const int* m = (id < 8) ? (src_mask + (size_t)b * TSRC) : (tgt_mask + (size_t)b * TTGT);
    const int T  = (id < 8) ? TSRC : TTGT;
    int s = 0;
    for (int i = t; i < T; i += 256) s += m[i];
#pragma unroll
    for (int off = 32; off > 0; off >>= 1) s += __shfl_down(s, off);
    __shared__ int red[4];
    if ((t & 63) == 0) red[t >> 6] = s;
    __syncthreads();
    if (t == 0) sizes[id] = red[0] + red[1] + red[2] + red[3];
  } else {
    const int i = (bx - (NCONV + 16)) * 256 + t;
    mask_out[i] = (float)src_mask[i];
  }
}

// ---- kernel 2: y = A @ W^T + bias, bf16, 256x128 tile with B-reuse ----------------
// Round-5 change vs proven round-0 (128x128, 4 waves): block covers 256M x 128N with
// 8 waves (4M x 2N); each wave keeps the EXACT round-0 64x64 / acc[4][4] profile and
// the EXACT 2-barrier sync schedule (issue global_load_lds -> barrier -> MFMA ->
// barrier). Effects: barriers per output row halved, B staged once per 256 rows
// instead of per 128 (A+B staging bytes per output -25%), grid 1024 -> 512.
// LDS 48 KB (As 32K + Bs 16K) -> 3 blocks/CU cap; grid gives 2/CU resident.
// Swizzle: bid%8 == Mt%8 -> all 8 N-blocks of an M-tile on one XCD (A L2-shared).
__global__ __launch_bounds__(512) void gemm_kernel(const __bf16* __restrict__ A,
                                                   const __bf16* __restrict__ Bw,
                                                   const float* __restrict__ bias,
                                                   const int* __restrict__ sizes,
                                                   __bf16* __restrict__ y) {
  const int bid = blockIdx.x;        // 0..511
  const int Mt  = bid & 63;          // m-tile (bid%8 == Mt%8 -> XCD affinity)
  const int Nt  = bid >> 6;          // 0..7
  const int n0 = Nt * 128;
  const int m0 = Mt * 256;           // 256-row tile; 2048%256==0 -> single batch
  const int b  = m0 >> 11;
  const int t0 = m0 & (TTGT - 1);
  if (t0 >= sizes[8 + b]) return;    // rows never gathered

  __shared__ __bf16 As[256 * BK];    // 32 KB
  __shared__ __bf16 Bs[128 * BK];    // 16 KB

  const int tid  = threadIdx.x;      // 0..511
  const int lane = tid & 63;
  const int wave = tid >> 6;         // 0..7
  const int wm   = (wave >> 1) * 64; // 4 m-slots of 64
  const int wn   = (wave & 1) * 64;  // 2 n-slots of 64
  const int lr   = lane & 15;
  const int quad = lane >> 4;

  // staging: 512 threads, thread t owns LDS elems [tid*8, tid*8+8)
  //          = row (q*64 + tid/8), col (tid%8)*8 for issue q (8 KB / issue)
  const int srow = tid >> 3;         // 0..63
  const int scol = (tid & 7) * 8;
  const __bf16* gA = A  + ((size_t)(m0 + srow)) * CH + scol;
  const __bf16* gB = Bw + ((size_t)(n0 + srow)) * CH + scol;
  __bf16* lA = As + tid * 8;
  __bf16* lB = Bs + tid * 8;

  f32x4 acc[4][4];
  const f32x4 z = {0.f, 0.f, 0.f, 0.f};
#pragma unroll
  for (int i = 0; i < 4; ++i)
#pragma unroll
    for (int j = 0; j < 4; ++j) acc[i][j] = z;

  for (int kb = 0; kb < CH; kb += BK) {
#pragma unroll
    for (int q = 0; q < 4; ++q)
      async16(gA + (size_t)q * 64 * CH + kb, lA + q * 4096);
#pragma unroll
    for (int q = 0; q < 2; ++q)
      async16(gB + (size_t)q * 64 * CH + kb, lB + q * 4096);
    __syncthreads();
#pragma unroll
    for (int ko = 0; ko < 2; ++ko) {
      bf16x8 af[4], bf[4];
#pragma unroll
      for (int i = 0; i < 4; ++i)
        af[i] = *(const bf16x8*)(As + (wm + i * 16 + lr) * BK + ko * 32 + quad * 8);
#pragma unroll
      for (int j = 0; j < 4; ++j)
        bf[j] = *(const bf16x8*)(Bs + (wn + j * 16 + lr) * BK + ko * 32 + quad * 8);
#pragma unroll
      for (int i = 0; i < 4; ++i)
#pragma unroll
        for (int j = 0; j < 4; ++j)
          acc[i][j] = __builtin_amdgcn_mfma_f32_16x16x32_bf16(af[i], bf[j], acc[i][j], 0, 0, 0);
    }
    __syncthreads();
  }

  // epilogue: C/D layout col = lane&15, row = quad*4 + reg; store bf16
#pragma unroll
  for (int i = 0; i < 4; ++i) {
    const int mrow = m0 + wm + i * 16 + quad * 4;
#pragma unroll
    for (int j = 0; j < 4; ++j) {
      const int ncol = n0 + wn + j * 16 + lr;
      const float bv = bias[ncol];
      __bf16* yp = y + (size_t)mrow * CH + ncol;
#pragma unroll
      for (int r = 0; r < 4; ++r) yp[(size_t)r * CH] = (__bf16)(acc[i][j][r] + bv);
    }
  }
}

// ---- kernel 3: gather + LayerNorm, wave-per-row (no barriers) ----------------------
// Normal (cached) stores restored — round-4 showed NT stores cost +35 us because the
// 134 MB out stream fits the 256 MiB L3 and NT forced it to HBM. g/beta hoist kept.
__global__ __launch_bounds__(256) void ln_kernel(const __bf16* __restrict__ y,
                                                 const int* __restrict__ sizes,
                                                 const float* __restrict__ g,
                                                 const float* __restrict__ be,
                                                 float* __restrict__ out) {
  const int wid = (blockIdx.x * 256 + threadIdx.x) >> 6;  // 0..8191
  const int l   = threadIdx.x & 63;

  // hoist gamma/beta: this wave always touches the same 16 channels per lane
  float gr[16], br[16];
#pragma unroll
  for (int h = 0; h < 2; ++h) {
    const int base = h * 512 + l * 8;
    *(f32x4*)(gr + h * 8)     = *(const f32x4*)(g + base);
    *(f32x4*)(gr + h * 8 + 4) = *(const f32x4*)(g + base + 4);
    *(f32x4*)(br + h * 8)     = *(const f32x4*)(be + base);
    *(f32x4*)(br + h * 8 + 4) = *(const f32x4*)(be + base + 4);
  }

#pragma unroll
  for (int rr = 0; rr < 4; ++rr) {
    const int row = wid + rr * 8192;        // 0..32767
    const int b   = row >> 12;
    const int j   = row & (TSRC - 1);
    const int ss  = sizes[b];
    const int tg  = sizes[8 + b];
    float v[16];
    if (j < ss) {
      const int den = (ss > 0) ? ss : 1;
      int ii = (int)(((long long)j * (long long)tg) / den);
      const int hi = ((tg > 1) ? tg : 1) - 1;
      ii = (ii > hi) ? hi : ((ii < 0) ? 0 : ii);
      const __bf16* yr = y + ((size_t)b * TTGT + ii) * CH;
      const bf16x8 u0 = *(const bf16x8*)(yr + l * 8);
      const bf16x8 u1 = *(const bf16x8*)(yr + 512 + l * 8);
#pragma unroll
      for (int k = 0; k < 8; ++k) { v[k] = (float)u0[k]; v[8 + k] = (float)u1[k]; }
    } else {
#pragma unroll
      for (int k = 0; k < 16; ++k) v[k] = 0.f;
    }
    float s = 0.f, q = 0.f;
#pragma unroll
    for (int k = 0; k < 16; ++k) { s += v[k]; q += v[k] * v[k]; }
#pragma unroll
    for (int off = 32; off > 0; off >>= 1) {
      s += __shfl_xor(s, off);
      q += __shfl_xor(q, off);
    }
    const float mu = s * (1.0f / CH);
    float var = q * (1.0f / CH) - mu * mu;
    var = fmaxf(var, 0.0f);
    const float rs = rsqrtf(var + 1e-5f);
    float* orow = out + (size_t)row * CH;
#pragma unroll
    for (int h = 0; h < 2; ++h) {
      const int base = h * 512 + l * 8;
      f32x4 o0, o1;
      o0[0] = (v[h * 8 + 0] - mu) * rs * gr[h * 8 + 0] + br[h * 8 + 0];
      o0[1] = (v[h * 8 + 1] - mu) * rs * gr[h * 8 + 1] + br[h * 8 + 1];
      o0[2] = (v[h * 8 + 2] - mu) * rs * gr[h * 8 + 2] + br[h * 8 + 2];
      o0[3] = (v[h * 8 + 3] - mu) * rs * gr[h * 8 + 3] + br[h * 8 + 3];
      o1[0] = (v[h * 8 + 4] - mu) * rs * gr[h * 8 + 4] + br[h * 8 + 4];
      o1[1] = (v[h * 8 + 5] - mu) * rs * gr[h * 8 + 5] + br[h * 8 + 5];
      o1[2] = (v[h * 8 + 6] - mu) * rs * gr[h * 8 + 6] + br[h * 8 + 6];
      o1[3] = (v[h * 8 + 7] - mu) * rs * gr[h * 8 + 7] + br[h * 8 + 7];
      *(f32x4*)(orow + base)     = o0;
      *(f32x4*)(orow + base + 4) = o1;
    }
  }
}

// ---------------- fallback: fully self-contained, no workspace needed ---------------
__global__ __launch_bounds__(256) void fallback_kernel(const float* __restrict__ tgt,
                                                       const int* __restrict__ src_mask,
                                                       const int* __restrict__ tgt_mask,
                                                       const float* __restrict__ W,
                                                       const float* __restrict__ bias,
                                                       const float* __restrict__ g,
                                                       const float* __restrict__ be,
                                                       float* __restrict__ out,
                                                       float* __restrict__ mask_out) {
  const int bx = blockIdx.x;
  const int b  = bx >> 12;
  const int j  = bx & (TSRC - 1);
  const int t  = threadIdx.x;
  int s1 = 0, s2 = 0;
  for (int i = t; i < TSRC; i += 256) s1 += src_mask[(size_t)b * TSRC + i];
  for (int i = t; i < TTGT; i += 256) s2 += tgt_mask[(size_t)b * TTGT + i];
#pragma unroll
  for (int off = 32; off > 0; off >>= 1) { s1 += __shfl_down(s1, off); s2 += __shfl_down(s2, off); }
  __shared__ int ired[8];
  if ((t & 63) == 0) { ired[t >> 6] = s1; ired[4 + (t >> 6)] = s2; }
  __syncthreads();
  const int ss = ired[0] + ired[1] + ired[2] + ired[3];
  const int tg = ired[4] + ired[5] + ired[6] + ired[7];
  const bool valid = j < ss;
  int ii = 0;
  if (valid) {
    const int den = (ss > 0) ? ss : 1;
    ii = (int)(((long long)j * (long long)tg) / den);
    const int hi = ((tg > 1) ? tg : 1) - 1;
    if (ii > hi) ii = hi;
    if (ii < 0) ii = 0;
  }
  __shared__ float trow[CH];
  const float* tr = tgt + ((size_t)b * TTGT + ii) * CH;
  for (int i = t; i < CH; i += 256) trow[i] = valid ? tr[i] : 0.0f;
  __syncthreads();
  float4 v = make_float4(0.f, 0.f, 0.f, 0.f);
  if (valid) {
    float a0 = 0.f, a1 = 0.f, a2 = 0.f, a3 = 0.f;
    const float* w0 = W + (size_t)(4 * t + 0) * CH;
    const float* w1 = W + (size_t)(4 * t + 1) * CH;
    const float* w2 = W + (size_t)(4 * t + 2) * CH;
    const float* w3 = W + (size_t)(4 * t + 3) * CH;
    for (int k = 0; k < CH; ++k) {
      const float x = trow[k];
      a0 += x * w0[k]; a1 += x * w1[k]; a2 += x * w2[k]; a3 += x * w3[k];
    }
    v.x = a0 + bias[4 * t + 0];
    v.y = a1 + bias[4 * t + 1];
    v.z = a2 + bias[4 * t + 2];
    v.w = a3 + bias[4 * t + 3];
  }
  float s  = v.x + v.y + v.z + v.w;
  float sq = v.x * v.x + v.y * v.y + v.z * v.z + v.w * v.w;
#pragma unroll
  for (int off = 32; off > 0; off >>= 1) {
    s  += __shfl_down(s, off);
    sq += __shfl_down(sq, off);
  }
  __shared__ float red[8];
  __shared__ float stats[2];
  if ((t & 63) == 0) { red[t >> 6] = s; red[4 + (t >> 6)] = sq; }
  __syncthreads();
  if (t == 0) {
    const float S  = red[0] + red[1] + red[2] + red[3];
    const float Q  = red[4] + red[5] + red[6] + red[7];
    const float mu = S * (1.0f / CH);
    float var = Q * (1.0f / CH) - mu * mu;
    var = fmaxf(var, 0.0f);
    stats[0] = mu;
    stats[1] = rsqrtf(var + 1e-5f);
  }
  __syncthreads();
  const float mu = stats[0], rs = stats[1];
  const float4 gg = ((const float4*)g)[t];
  const float4 bb = ((const float4*)be)[t];
  float4 o;
  o.x = (v.x - mu) * rs * gg.x + bb.x;
  o.y = (v.y - mu) * rs * gg.y + bb.y;
  o.z = (v.z - mu) * rs * gg.z + bb.z;
  o.w = (v.w - mu) * rs * gg.w + bb.w;
  ((float4*)(out + ((size_t)b * TSRC + j) * CH))[t] = o;
  if (t == 0) mask_out[bx] = (float)src_mask[bx];
}

extern "C" void kernel_launch(void* const* d_in, const int* in_sizes, int n_in,
                              void* d_out, int out_size, void* d_ws, size_t ws_size,
                              hipStream_t stream) {
  (void)in_sizes; (void)n_in; (void)out_size;
  // setup_inputs order: src, src_mask, tgt, tgt_mask, conv_w, conv_b, ln_g, ln_b
  const int*   src_mask = (const int*)d_in[1];
  const float* tgt      = (const float*)d_in[2];
  const int*   tgt_mask = (const int*)d_in[3];
  const float* conv_w   = (const float*)d_in[4];
  const float* conv_b   = (const float*)d_in[5];
  const float* ln_g     = (const float*)d_in[6];
  const float* ln_b     = (const float*)d_in[7];

  float* out      = (float*)d_out;
  float* mask_out = out + (size_t)NB * TSRC * CH;   // second tuple element, as f32

  const size_t M       = (size_t)NB * TTGT;              // 16384 rows
  const size_t off_abf = 256;
  const size_t off_wbf = off_abf + M * CH * 2;           // +32 MiB
  const size_t off_y   = off_wbf + (size_t)CH * CH * 2;  // +2 MiB
  const size_t need    = off_y + M * CH * 2;             // +32 MiB => ~66 MiB

  if (ws_size >= need) {
    int*    sizes = (int*)d_ws;
    __bf16* Abf   = (__bf16*)((char*)d_ws + off_abf);
    __bf16* Wbf   = (__bf16*)((char*)d_ws + off_wbf);
    __bf16* y     = (__bf16*)((char*)d_ws + off_y);
    prep_kernel<<<NB * TTGT + CH + 16 + 128, 256, 0, stream>>>(tgt, conv_w, src_mask, tgt_mask,
                                                               Abf, Wbf, sizes, mask_out);
    gemm_kernel<<<512, 512, 0, stream>>>(Abf, Wbf, conv_b, sizes, y);
    ln_kernel<<<2048, 256, 0, stream>>>(y, sizes, ln_g, ln_b, out);
  } else {
    fallback_kernel<<<NB * TSRC, 256, 0, stream>>>(tgt, src_mask, tgt_mask, conv_w, conv_b,
                                                   ln_g, ln_b, out, mask_out);
  }
}

// Round 6
// 302.556 us; speedup vs baseline: 1.1844x; 1.0124x over previous
//
#include <hip/hip_runtime.h>

#define NB   8
#define TSRC 4096
#define TTGT 2048
#define CH   1024   // C_IN == C_OUT

typedef __attribute__((ext_vector_type(4))) float  f32x4;
typedef __attribute__((ext_vector_type(8))) __bf16 bf16x8;
typedef __attribute__((ext_vector_type(4))) __bf16 bf16x4;

__device__ __forceinline__ void async16(const void* g, void* l) {
  __builtin_amdgcn_global_load_lds((const __attribute__((address_space(1))) void*)g,
                                   (__attribute__((address_space(3))) void*)l, 16, 0, 0);
}

// ---- kernel 1: fused prep = f32->bf16 convert (tgt + W) + ragged sizes + mask out --
// (round-0 proven version)
__global__ __launch_bounds__(256) void prep_kernel(const float* __restrict__ tgt,
                                                   const float* __restrict__ W,
                                                   const int* __restrict__ src_mask,
                                                   const int* __restrict__ tgt_mask,
                                                   __bf16* __restrict__ Abf,
                                                   __bf16* __restrict__ Wbf,
                                                   int* __restrict__ sizes,
                                                   float* __restrict__ mask_out) {
  const int bx = blockIdx.x;
  const int t  = threadIdx.x;
  const int NCONV = NB * TTGT + CH;          // 17408
  if (bx < NCONV) {
    const float* sp;
    __bf16* dp;
    if (bx < NB * TTGT) { sp = tgt + (size_t)bx * CH; dp = Abf + (size_t)bx * CH; }
    else { const int r = bx - NB * TTGT; sp = W + (size_t)r * CH; dp = Wbf + (size_t)r * CH; }
    const float4 v = ((const float4*)sp)[t];
    bf16x4 u = {(__bf16)v.x, (__bf16)v.y, (__bf16)v.z, (__bf16)v.w};
    *(bf16x4*)(dp + t * 4) = u;
  } else if (bx < NCONV + 16) {
    const int id = bx - NCONV;               // 0..7 src, 8..15 tgt
    const int b  = id & 7;
    const int* m = (id < 8) ? (src_mask + (size_t)b * TSRC) : (tgt_mask + (size_t)b * TTGT);
    const int T  = (id < 8) ? TSRC : TTGT;
    int s = 0;
    for (int i = t; i < T; i += 256) s += m[i];
#pragma unroll
    for (int off = 32; off > 0; off >>= 1) s += __shfl_down(s, off);
    __shared__ int red[4];
    if ((t & 63) == 0) red[t >> 6] = s;
    __syncthreads();
    if (t == 0) sizes[id] = red[0] + red[1] + red[2] + red[3];
  } else {
    const int i = (bx - (NCONV + 16)) * 256 + t;
    mask_out[i] = (float)src_mask[i];
  }
}

// ---- kernel 2: y = A @ W^T + bias, 256x128 tile, BK=32 ping-pong double-buffer ----
// Round-6 change vs round-5 (same 256M x 128N tile, 8 waves 4x2, B-reuse): the K-loop
// is restructured to the T3 "minimum 2-phase" recipe with plain __syncthreads
// semantics:  stage(next half-K into buf^1) -> compute(buf) -> __syncthreads.
// One barrier per half-step, and the staging loads get the whole compute phase
// (16 MFMAs x 8 waves) to land before the barrier drains them, instead of being
// drained immediately with zero cover. Two BK=32 half-buffers fit in the SAME
// 48 KB LDS footprint as round-5's single BK=64 buffer -> occupancy unchanged
// (2 blocks/CU). Fragment-read row stride drops 128B -> 64B (16-way -> 8-way
// aliasing on ds_read_b128).
// Swizzle: bid%8 == Mt%8 -> all 8 N-blocks of an M-tile on one XCD (A L2-shared).
__global__ __launch_bounds__(512) void gemm_kernel(const __bf16* __restrict__ A,
                                                   const __bf16* __restrict__ Bw,
                                                   const float* __restrict__ bias,
                                                   const int* __restrict__ sizes,
                                                   __bf16* __restrict__ y) {
  const int bid = blockIdx.x;        // 0..511
  const int Mt  = bid & 63;          // m-tile (bid%8 == Mt%8 -> XCD affinity)
  const int Nt  = bid >> 6;          // 0..7
  const int n0 = Nt * 128;
  const int m0 = Mt * 256;           // 256-row tile; batch-aligned
  const int b  = m0 >> 11;
  const int t0 = m0 & (TTGT - 1);
  if (t0 >= sizes[8 + b]) return;    // rows never gathered

  __shared__ __bf16 As[2 * 256 * 32];  // 2 x 16 KB
  __shared__ __bf16 Bs[2 * 128 * 32];  // 2 x 8 KB   (48 KB total)

  const int tid  = threadIdx.x;      // 0..511
  const int lane = tid & 63;
  const int wave = tid >> 6;         // 0..7
  const int wm   = (wave >> 1) * 64; // 4 m-slots of 64
  const int wn   = (wave & 1) * 64;  // 2 n-slots of 64
  const int lr   = lane & 15;
  const int quad = lane >> 4;

  // staging: one issue = 512 thr x 16B = 8 KB = 128 rows of a 32-col (64B) K-slice.
  //   thread t -> row (t>>2), elem col (t&3)*8 ; LDS dest linear = tid*8 elems.
  //   A: 2 issues (rows 0-127, 128-255); B: 1 issue (rows 0-127).
  const int srow = tid >> 2;         // 0..127
  const int scol = (tid & 3) * 8;    // 0,8,16,24
  const __bf16* gA = A  + ((size_t)(m0 + srow)) * CH + scol;
  const __bf16* gB = Bw + ((size_t)(n0 + srow)) * CH + scol;
  __bf16* lA = As + tid * 8;
  __bf16* lB = Bs + tid * 8;

  f32x4 acc[4][4];
  const f32x4 z = {0.f, 0.f, 0.f, 0.f};
#pragma unroll
  for (int i = 0; i < 4; ++i)
#pragma unroll
    for (int j = 0; j < 4; ++j) acc[i][j] = z;

  // prologue: stage half-tile 0 into buffer 0
  async16(gA, lA);
  async16(gA + (size_t)128 * CH, lA + 4096);
  async16(gB, lB);
  __syncthreads();

  const int NIT = CH / 32;           // 32 half-steps
  for (int it = 0; it < NIT; ++it) {
    const int cur = it & 1;
    // issue next half-tile's stage FIRST (into the other buffer) — covered by MFMAs
    if (it + 1 < NIT) {
      const int nxt = cur ^ 1;
      const int kb  = (it + 1) * 32;
      async16(gA + kb, lA + nxt * 8192);
      async16(gA + (size_t)128 * CH + kb, lA + nxt * 8192 + 4096);
      async16(gB + kb, lB + nxt * 4096);
    }
    // compute current half-tile (K=32 -> one MFMA per acc cell)
    const __bf16* Ab = As + cur * 8192;
    const __bf16* Bb = Bs + cur * 4096;
    bf16x8 af[4], bf[4];
#pragma unroll
    for (int i = 0; i < 4; ++i)
      af[i] = *(const bf16x8*)(Ab + (wm + i * 16 + lr) * 32 + quad * 8);
#pragma unroll
    for (int j = 0; j < 4; ++j)
      bf[j] = *(const bf16x8*)(Bb + (wn + j * 16 + lr) * 32 + quad * 8);
#pragma unroll
    for (int i = 0; i < 4; ++i)
#pragma unroll
      for (int j = 0; j < 4; ++j)
        acc[i][j] = __builtin_amdgcn_mfma_f32_16x16x32_bf16(af[i], bf[j], acc[i][j], 0, 0, 0);
    // single barrier per half-step: drains next-stage loads (now mostly landed)
    // and guarantees all waves are done reading buf[cur] before it is re-staged.
    __syncthreads();
  }

  // epilogue: C/D layout col = lane&15, row = quad*4 + reg; store bf16
#pragma unroll
  for (int i = 0; i < 4; ++i) {
    const int mrow = m0 + wm + i * 16 + quad * 4;
#pragma unroll
    for (int j = 0; j < 4; ++j) {
      const int ncol = n0 + wn + j * 16 + lr;
      const float bv = bias[ncol];
      __bf16* yp = y + (size_t)mrow * CH + ncol;
#pragma unroll
      for (int r = 0; r < 4; ++r) yp[(size_t)r * CH] = (__bf16)(acc[i][j][r] + bv);
    }
  }
}

// ---- kernel 3: gather + LayerNorm, wave-per-row (no barriers) ----------------------
// (round-5 proven version: cached stores, g/beta hoisted)
__global__ __launch_bounds__(256) void ln_kernel(const __bf16* __restrict__ y,
                                                 const int* __restrict__ sizes,
                                                 const float* __restrict__ g,
                                                 const float* __restrict__ be,
                                                 float* __restrict__ out) {
  const int wid = (blockIdx.x * 256 + threadIdx.x) >> 6;  // 0..8191
  const int l   = threadIdx.x & 63;

  float gr[16], br[16];
#pragma unroll
  for (int h = 0; h < 2; ++h) {
    const int base = h * 512 + l * 8;
    *(f32x4*)(gr + h * 8)     = *(const f32x4*)(g + base);
    *(f32x4*)(gr + h * 8 + 4) = *(const f32x4*)(g + base + 4);
    *(f32x4*)(br + h * 8)     = *(const f32x4*)(be + base);
    *(f32x4*)(br + h * 8 + 4) = *(const f32x4*)(be + base + 4);
  }

#pragma unroll
  for (int rr = 0; rr < 4; ++rr) {
    const int row = wid + rr * 8192;        // 0..32767
    const int b   = row >> 12;
    const int j   = row & (TSRC - 1);
    const int ss  = sizes[b];
    const int tg  = sizes[8 + b];
    float v[16];
    if (j < ss) {
      const int den = (ss > 0) ? ss : 1;
      int ii = (int)(((long long)j * (long long)tg) / den);
      const int hi = ((tg > 1) ? tg : 1) - 1;
      ii = (ii > hi) ? hi : ((ii < 0) ? 0 : ii);
      const __bf16* yr = y + ((size_t)b * TTGT + ii) * CH;
      const bf16x8 u0 = *(const bf16x8*)(yr + l * 8);
      const bf16x8 u1 = *(const bf16x8*)(yr + 512 + l * 8);
#pragma unroll
      for (int k = 0; k < 8; ++k) { v[k] = (float)u0[k]; v[8 + k] = (float)u1[k]; }
    } else {
#pragma unroll
      for (int k = 0; k < 16; ++k) v[k] = 0.f;
    }
    float s = 0.f, q = 0.f;
#pragma unroll
    for (int k = 0; k < 16; ++k) { s += v[k]; q += v[k] * v[k]; }
#pragma unroll
    for (int off = 32; off > 0; off >>= 1) {
      s += __shfl_xor(s, off);
      q += __shfl_xor(q, off);
    }
    const float mu = s * (1.0f / CH);
    float var = q * (1.0f / CH) - mu * mu;
    var = fmaxf(var, 0.0f);
    const float rs = rsqrtf(var + 1e-5f);
    float* orow = out + (size_t)row * CH;
#pragma unroll
    for (int h = 0; h < 2; ++h) {
      const int base = h * 512 + l * 8;
      f32x4 o0, o1;
      o0[0] = (v[h * 8 + 0] - mu) * rs * gr[h * 8 + 0] + br[h * 8 + 0];
      o0[1] = (v[h * 8 + 1] - mu) * rs * gr[h * 8 + 1] + br[h * 8 + 1];
      o0[2] = (v[h * 8 + 2] - mu) * rs * gr[h * 8 + 2] + br[h * 8 + 2];
      o0[3] = (v[h * 8 + 3] - mu) * rs * gr[h * 8 + 3] + br[h * 8 + 3];
      o1[0] = (v[h * 8 + 4] - mu) * rs * gr[h * 8 + 4] + br[h * 8 + 4];
      o1[1] = (v[h * 8 + 5] - mu) * rs * gr[h * 8 + 5] + br[h * 8 + 5];
      o1[2] = (v[h * 8 + 6] - mu) * rs * gr[h * 8 + 6] + br[h * 8 + 6];
      o1[3] = (v[h * 8 + 7] - mu) * rs * gr[h * 8 + 7] + br[h * 8 + 7];
      *(f32x4*)(orow + base)     = o0;
      *(f32x4*)(orow + base + 4) = o1;
    }
  }
}

// ---------------- fallback: fully self-contained, no workspace needed ---------------
__global__ __launch_bounds__(256) void fallback_kernel(const float* __restrict__ tgt,
                                                       const int* __restrict__ src_mask,
                                                       const int* __restrict__ tgt_mask,
                                                       const float* __restrict__ W,
                                                       const float* __restrict__ bias,
                                                       const float* __restrict__ g,
                                                       const float* __restrict__ be,
                                                       float* __restrict__ out,
                                                       float* __restrict__ mask_out) {
  const int bx = blockIdx.x;
  const int b  = bx >> 12;
  const int j  = bx & (TSRC - 1);
  const int t  = threadIdx.x;
  int s1 = 0, s2 = 0;
  for (int i = t; i < TSRC; i += 256) s1 += src_mask[(size_t)b * TSRC + i];
  for (int i = t; i < TTGT; i += 256) s2 += tgt_mask[(size_t)b * TTGT + i];
#pragma unroll
  for (int off = 32; off > 0; off >>= 1) { s1 += __shfl_down(s1, off); s2 += __shfl_down(s2, off); }
  __shared__ int ired[8];
  if ((t & 63) == 0) { ired[t >> 6] = s1; ired[4 + (t >> 6)] = s2; }
  __syncthreads();
  const int ss = ired[0] + ired[1] + ired[2] + ired[3];
  const int tg = ired[4] + ired[5] + ired[6] + ired[7];
  const bool valid = j < ss;
  int ii = 0;
  if (valid) {
    const int den = (ss > 0) ? ss : 1;
    ii = (int)(((long long)j * (long long)tg) / den);
    const int hi = ((tg > 1) ? tg : 1) - 1;
    if (ii > hi) ii = hi;
    if (ii < 0) ii = 0;
  }
  __shared__ float trow[CH];
  const float* tr = tgt + ((size_t)b * TTGT + ii) * CH;
  for (int i = t; i < CH; i += 256) trow[i] = valid ? tr[i] : 0.0f;
  __syncthreads();
  float4 v = make_float4(0.f, 0.f, 0.f, 0.f);
  if (valid) {
    float a0 = 0.f, a1 = 0.f, a2 = 0.f, a3 = 0.f;
    const float* w0 = W + (size_t)(4 * t + 0) * CH;
    const float* w1 = W + (size_t)(4 * t + 1) * CH;
    const float* w2 = W + (size_t)(4 * t + 2) * CH;
    const float* w3 = W + (size_t)(4 * t + 3) * CH;
    for (int k = 0; k < CH; ++k) {
      const float x = trow[k];
      a0 += x * w0[k]; a1 += x * w1[k]; a2 += x * w2[k]; a3 += x * w3[k];
    }
    v.x = a0 + bias[4 * t + 0];
    v.y = a1 + bias[4 * t + 1];
    v.z = a2 + bias[4 * t + 2];
    v.w = a3 + bias[4 * t + 3];
  }
  float s  = v.x + v.y + v.z + v.w;
  float sq = v.x * v.x + v.y * v.y + v.z * v.z + v.w * v.w;
#pragma unroll
  for (int off = 32; off > 0; off >>= 1) {
    s  += __shfl_down(s, off);
    sq += __shfl_down(sq, off);
  }
  __shared__ float red[8];
  __shared__ float stats[2];
  if ((t & 63) == 0) { red[t >> 6] = s; red[4 + (t >> 6)] = sq; }
  __syncthreads();
  if (t == 0) {
    const float S  = red[0] + red[1] + red[2] + red[3];
    const float Q  = red[4] + red[5] + red[6] + red[7];
    const float mu = S * (1.0f / CH);
    float var = Q * (1.0f / CH) - mu * mu;
    var = fmaxf(var, 0.0f);
    stats[0] = mu;
    stats[1] = rsqrtf(var + 1e-5f);
  }
  __syncthreads();
  const float mu = stats[0], rs = stats[1];
  const float4 gg = ((const float4*)g)[t];
  const float4 bb = ((const float4*)be)[t];
  float4 o;
  o.x = (v.x - mu) * rs * gg.x + bb.x;
  o.y = (v.y - mu) * rs * gg.y + bb.y;
  o.z = (v.z - mu) * rs * gg.z + bb.z;
  o.w = (v.w - mu) * rs * gg.w + bb.w;
  ((float4*)(out + ((size_t)b * TSRC + j) * CH))[t] = o;
  if (t == 0) mask_out[bx] = (float)src_mask[bx];
}

extern "C" void kernel_launch(void* const* d_in, const int* in_sizes, int n_in,
                              void* d_out, int out_size, void* d_ws, size_t ws_size,
                              hipStream_t stream) {
  (void)in_sizes; (void)n_in; (void)out_size;
  // setup_inputs order: src, src_mask, tgt, tgt_mask, conv_w, conv_b, ln_g, ln_b
  const int*   src_mask = (const int*)d_in[1];
  const float* tgt      = (const float*)d_in[2];
  const int*   tgt_mask = (const int*)d_in[3];
  const float* conv_w   = (const float*)d_in[4];
  const float* conv_b   = (const float*)d_in[5];
  const float* ln_g     = (const float*)d_in[6];
  const float* ln_b     = (const float*)d_in[7];

  float* out      = (float*)d_out;
  float* mask_out = out + (size_t)NB * TSRC * CH;   // second tuple element, as f32

  const size_t M       = (size_t)NB * TTGT;              // 16384 rows
  const size_t off_abf = 256;
  const size_t off_wbf = off_abf + M * CH * 2;           // +32 MiB
  const size_t off_y   = off_wbf + (size_t)CH * CH * 2;  // +2 MiB
  const size_t need    = off_y + M * CH * 2;             // +32 MiB => ~66 MiB

  if (ws_size >= need) {
    int*    sizes = (int*)d_ws;
    __bf16* Abf   = (__bf16*)((char*)d_ws + off_abf);
    __bf16* Wbf   = (__bf16*)((char*)d_ws + off_wbf);
    __bf16* y     = (__bf16*)((char*)d_ws + off_y);
    prep_kernel<<<NB * TTGT + CH + 16 + 128, 256, 0, stream>>>(tgt, conv_w, src_mask, tgt_mask,
                                                               Abf, Wbf, sizes, mask_out);
    gemm_kernel<<<512, 512, 0, stream>>>(Abf, Wbf, conv_b, sizes, y);
    ln_kernel<<<2048, 256, 0, stream>>>(y, sizes, ln_g, ln_b, out);
  } else {
    fallback_kernel<<<NB * TSRC, 256, 0, stream>>>(tgt, src_mask, tgt_mask, conv_w, conv_b,
                                                   ln_g, ln_b, out, mask_out);
  }
}

// Round 7
// 301.745 us; speedup vs baseline: 1.1876x; 1.0027x over previous
//
#include <hip/hip_runtime.h>

#define NB   8
#define TSRC 4096
#define TTGT 2048
#define CH   1024   // C_IN == C_OUT

typedef __attribute__((ext_vector_type(4))) float  f32x4;
typedef __attribute__((ext_vector_type(8))) __bf16 bf16x8;
typedef __attribute__((ext_vector_type(4))) __bf16 bf16x4;

__device__ __forceinline__ void async16(const void* g, void* l) {
  __builtin_amdgcn_global_load_lds((const __attribute__((address_space(1))) void*)g,
                                   (__attribute__((address_space(3))) void*)l, 16, 0, 0);
}

// ---- kernel 1: fused prep = f32->bf16 convert (tgt + W) + ragged sizes + mask out --
// (round-0 proven version)
__global__ __launch_bounds__(256) void prep_kernel(const float* __restrict__ tgt,
                                                   const float* __restrict__ W,
                                                   const int* __restrict__ src_mask,
                                                   const int* __restrict__ tgt_mask,
                                                   __bf16* __restrict__ Abf,
                                                   __bf16* __restrict__ Wbf,
                                                   int* __restrict__ sizes,
                                                   float* __restrict__ mask_out) {
  const int bx = blockIdx.x;
  const int t  = threadIdx.x;
  const int NCONV = NB * TTGT + CH;          // 17408
  if (bx < NCONV) {
    const float* sp;
    __bf16* dp;
    if (bx < NB * TTGT) { sp = tgt + (size_t)bx * CH; dp = Abf + (size_t)bx * CH; }
    else { const int r = bx - NB * TTGT; sp = W + (size_t)r * CH; dp = Wbf + (size_t)r * CH; }
    const float4 v = ((const float4*)sp)[t];
    bf16x4 u = {(__bf16)v.x, (__bf16)v.y, (__bf16)v.z, (__bf16)v.w};
    *(bf16x4*)(dp + t * 4) = u;
  } else if (bx < NCONV + 16) {
    const int id = bx - NCONV;               // 0..7 src, 8..15 tgt
    const int b  = id & 7;
    const int* m = (id < 8) ? (src_mask + (size_t)b * TSRC) : (tgt_mask + (size_t)b * TTGT);
    const int T  = (id < 8) ? TSRC : TTGT;
    int s = 0;
    for (int i = t; i < T; i += 256) s += m[i];
#pragma unroll
    for (int off = 32; off > 0; off >>= 1) s += __shfl_down(s, off);
    __shared__ int red[4];
    if ((t & 63) == 0) red[t >> 6] = s;
    __syncthreads();
    if (t == 0) sizes[id] = red[0] + red[1] + red[2] + red[3];
  } else {
    const int i = (bx - (NCONV + 16)) * 256 + t;
    mask_out[i] = (float)src_mask[i];
  }
}

// ---- kernel 2: y = A @ W^T + bias, 256x128 tile, BK=32 ping-pong + counted vmcnt --
// Round-7 change vs round-6 (same tile/waves/staging geometry): T4 counted-vmcnt.
// Round-6's __syncthreads drained vmcnt(0) at every barrier — the just-issued
// next-tile loads only had the same iteration's MFMAs (~150 cyc) to land; residual
// L2/HBM latency was paid raw at each of 32 barriers. Now:
//   stage(it+1)  [3 global_load_lds, stays IN FLIGHT across the barrier]
//   s_waitcnt vmcnt(3)   <- in-order VMEM retirement => waits only for stage(it),
//                           which has had a FULL iteration to land  => ~0 stall
//   s_barrier            (b1: buf[cur] complete for all waves)
//   compute(cur)         (ds_read results consumed by MFMAs => LDS reads retired)
//   s_barrier            (b2: all reads of buf[cur] done before it is re-staged)
// Both branches are block-uniform; per-wave vmcnt counts are symmetric (every
// thread issues exactly 3 loads per iteration). Depth-1 instance of the verified
// 8-phase template's phase-4/8 idiom.
// Swizzle: bid%8 == Mt%8 -> all 8 N-blocks of an M-tile on one XCD (A L2-shared).
__global__ __launch_bounds__(512) void gemm_kernel(const __bf16* __restrict__ A,
                                                   const __bf16* __restrict__ Bw,
                                                   const float* __restrict__ bias,
                                                   const int* __restrict__ sizes,
                                                   __bf16* __restrict__ y) {
  const int bid = blockIdx.x;        // 0..511
  const int Mt  = bid & 63;          // m-tile (bid%8 == Mt%8 -> XCD affinity)
  const int Nt  = bid >> 6;          // 0..7
  const int n0 = Nt * 128;
  const int m0 = Mt * 256;           // 256-row tile; batch-aligned
  const int b  = m0 >> 11;
  const int t0 = m0 & (TTGT - 1);
  if (t0 >= sizes[8 + b]) return;    // rows never gathered (block-uniform)

  __shared__ __bf16 As[2 * 256 * 32];  // 2 x 16 KB
  __shared__ __bf16 Bs[2 * 128 * 32];  // 2 x 8 KB   (48 KB total)

  const int tid  = threadIdx.x;      // 0..511
  const int lane = tid & 63;
  const int wave = tid >> 6;         // 0..7
  const int wm   = (wave >> 1) * 64; // 4 m-slots of 64
  const int wn   = (wave & 1) * 64;  // 2 n-slots of 64
  const int lr   = lane & 15;
  const int quad = lane >> 4;

  // staging: one issue = 512 thr x 16B = 8 KB = 128 rows of a 32-col (64B) K-slice.
  //   thread t -> row (t>>2), elem col (t&3)*8 ; LDS dest linear = tid*8 elems.
  //   A: 2 issues (rows 0-127, 128-255); B: 1 issue (rows 0-127).
  const int srow = tid >> 2;         // 0..127
  const int scol = (tid & 3) * 8;    // 0,8,16,24
  const __bf16* gA = A  + ((size_t)(m0 + srow)) * CH + scol;
  const __bf16* gB = Bw + ((size_t)(n0 + srow)) * CH + scol;
  __bf16* lA = As + tid * 8;
  __bf16* lB = Bs + tid * 8;

  f32x4 acc[4][4];
  const f32x4 z = {0.f, 0.f, 0.f, 0.f};
#pragma unroll
  for (int i = 0; i < 4; ++i)
#pragma unroll
    for (int j = 0; j < 4; ++j) acc[i][j] = z;

  // prologue: stage half-tile 0 into buffer 0 (3 loads in flight)
  async16(gA, lA);
  async16(gA + (size_t)128 * CH, lA + 4096);
  async16(gB, lB);

  const int NIT = CH / 32;           // 32 half-steps
  for (int it = 0; it < NIT; ++it) {
    const int cur = it & 1;
    if (it + 1 < NIT) {
      const int nxt = cur ^ 1;
      const int kb  = (it + 1) * 32;
      async16(gA + kb, lA + nxt * 8192);
      async16(gA + (size_t)128 * CH + kb, lA + nxt * 8192 + 4096);
      async16(gB + kb, lB + nxt * 4096);
      // wait only for stage(it)'s 3 loads; stage(it+1) stays in flight
      asm volatile("s_waitcnt vmcnt(3)" ::: "memory");
    } else {
      asm volatile("s_waitcnt vmcnt(0)" ::: "memory");
    }
    __builtin_amdgcn_s_barrier();    // b1: buf[cur] ready for all waves
    const __bf16* Ab = As + cur * 8192;
    const __bf16* Bb = Bs + cur * 4096;
    bf16x8 af[4], bf[4];
#pragma unroll
    for (int i = 0; i < 4; ++i)
      af[i] = *(const bf16x8*)(Ab + (wm + i * 16 + lr) * 32 + quad * 8);
#pragma unroll
    for (int j = 0; j < 4; ++j)
      bf[j] = *(const bf16x8*)(Bb + (wn + j * 16 + lr) * 32 + quad * 8);
#pragma unroll
    for (int i = 0; i < 4; ++i)
#pragma unroll
      for (int j = 0; j < 4; ++j)
        acc[i][j] = __builtin_amdgcn_mfma_f32_16x16x32_bf16(af[i], bf[j], acc[i][j], 0, 0, 0);
    __builtin_amdgcn_s_barrier();    // b2: reads of buf[cur] done before re-stage
  }

  // epilogue: C/D layout col = lane&15, row = quad*4 + reg; store bf16
#pragma unroll
  for (int i = 0; i < 4; ++i) {
    const int mrow = m0 + wm + i * 16 + quad * 4;
#pragma unroll
    for (int j = 0; j < 4; ++j) {
      const int ncol = n0 + wn + j * 16 + lr;
      const float bv = bias[ncol];
      __bf16* yp = y + (size_t)mrow * CH + ncol;
#pragma unroll
      for (int r = 0; r < 4; ++r) yp[(size_t)r * CH] = (__bf16)(acc[i][j][r] + bv);
    }
  }
}

// ---- kernel 3: gather + LayerNorm, wave-per-row (no barriers) ----------------------
// (round-5 proven version: cached stores, g/beta hoisted)
__global__ __launch_bounds__(256) void ln_kernel(const __bf16* __restrict__ y,
                                                 const int* __restrict__ sizes,
                                                 const float* __restrict__ g,
                                                 const float* __restrict__ be,
                                                 float* __restrict__ out) {
  const int wid = (blockIdx.x * 256 + threadIdx.x) >> 6;  // 0..8191
  const int l   = threadIdx.x & 63;

  float gr[16], br[16];
#pragma unroll
  for (int h = 0; h < 2; ++h) {
    const int base = h * 512 + l * 8;
    *(f32x4*)(gr + h * 8)     = *(const f32x4*)(g + base);
    *(f32x4*)(gr + h * 8 + 4) = *(const f32x4*)(g + base + 4);
    *(f32x4*)(br + h * 8)     = *(const f32x4*)(be + base);
    *(f32x4*)(br + h * 8 + 4) = *(const f32x4*)(be + base + 4);
  }

#pragma unroll
  for (int rr = 0; rr < 4; ++rr) {
    const int row = wid + rr * 8192;        // 0..32767
    const int b   = row >> 12;
    const int j   = row & (TSRC - 1);
    const int ss  = sizes[b];
    const int tg  = sizes[8 + b];
    float v[16];
    if (j < ss) {
      const int den = (ss > 0) ? ss : 1;
      int ii = (int)(((long long)j * (long long)tg) / den);
      const int hi = ((tg > 1) ? tg : 1) - 1;
      ii = (ii > hi) ? hi : ((ii < 0) ? 0 : ii);
      const __bf16* yr = y + ((size_t)b * TTGT + ii) * CH;
      const bf16x8 u0 = *(const bf16x8*)(yr + l * 8);
      const bf16x8 u1 = *(const bf16x8*)(yr + 512 + l * 8);
#pragma unroll
      for (int k = 0; k < 8; ++k) { v[k] = (float)u0[k]; v[8 + k] = (float)u1[k]; }
    } else {
#pragma unroll
      for (int k = 0; k < 16; ++k) v[k] = 0.f;
    }
    float s = 0.f, q = 0.f;
#pragma unroll
    for (int k = 0; k < 16; ++k) { s += v[k]; q += v[k] * v[k]; }
#pragma unroll
    for (int off = 32; off > 0; off >>= 1) {
      s += __shfl_xor(s, off);
      q += __shfl_xor(q, off);
    }
    const float mu = s * (1.0f / CH);
    float var = q * (1.0f / CH) - mu * mu;
    var = fmaxf(var, 0.0f);
    const float rs = rsqrtf(var + 1e-5f);
    float* orow = out + (size_t)row * CH;
#pragma unroll
    for (int h = 0; h < 2; ++h) {
      const int base = h * 512 + l * 8;
      f32x4 o0, o1;
      o0[0] = (v[h * 8 + 0] - mu) * rs * gr[h * 8 + 0] + br[h * 8 + 0];
      o0[1] = (v[h * 8 + 1] - mu) * rs * gr[h * 8 + 1] + br[h * 8 + 1];
      o0[2] = (v[h * 8 + 2] - mu) * rs * gr[h * 8 + 2] + br[h * 8 + 2];
      o0[3] = (v[h * 8 + 3] - mu) * rs * gr[h * 8 + 3] + br[h * 8 + 3];
      o1[0] = (v[h * 8 + 4] - mu) * rs * gr[h * 8 + 4] + br[h * 8 + 4];
      o1[1] = (v[h * 8 + 5] - mu) * rs * gr[h * 8 + 5] + br[h * 8 + 5];
      o1[2] = (v[h * 8 + 6] - mu) * rs * gr[h * 8 + 6] + br[h * 8 + 6];
      o1[3] = (v[h * 8 + 7] - mu) * rs * gr[h * 8 + 7] + br[h * 8 + 7];
      *(f32x4*)(orow + base)     = o0;
      *(f32x4*)(orow + base + 4) = o1;
    }
  }
}

// ---------------- fallback: fully self-contained, no workspace needed ---------------
__global__ __launch_bounds__(256) void fallback_kernel(const float* __restrict__ tgt,
                                                       const int* __restrict__ src_mask,
                                                       const int* __restrict__ tgt_mask,
                                                       const float* __restrict__ W,
                                                       const float* __restrict__ bias,
                                                       const float* __restrict__ g,
                                                       const float* __restrict__ be,
                                                       float* __restrict__ out,
                                                       float* __restrict__ mask_out) {
  const int bx = blockIdx.x;
  const int b  = bx >> 12;
  const int j  = bx & (TSRC - 1);
  const int t  = threadIdx.x;
  int s1 = 0, s2 = 0;
  for (int i = t; i < TSRC; i += 256) s1 += src_mask[(size_t)b * TSRC + i];
  for (int i = t; i < TTGT; i += 256) s2 += tgt_mask[(size_t)b * TTGT + i];
#pragma unroll
  for (int off = 32; off > 0; off >>= 1) { s1 += __shfl_down(s1, off); s2 += __shfl_down(s2, off); }
  __shared__ int ired[8];
  if ((t & 63) == 0) { ired[t >> 6] = s1; ired[4 + (t >> 6)] = s2; }
  __syncthreads();
  const int ss = ired[0] + ired[1] + ired[2] + ired[3];
  const int tg = ired[4] + ired[5] + ired[6] + ired[7];
  const bool valid = j < ss;
  int ii = 0;
  if (valid) {
    const int den = (ss > 0) ? ss : 1;
    ii = (int)(((long long)j * (long long)tg) / den);
    const int hi = ((tg > 1) ? tg : 1) - 1;
    if (ii > hi) ii = hi;
    if (ii < 0) ii = 0;
  }
  __shared__ float trow[CH];
  const float* tr = tgt + ((size_t)b * TTGT + ii) * CH;
  for (int i = t; i < CH; i += 256) trow[i] = valid ? tr[i] : 0.0f;
  __syncthreads();
  float4 v = make_float4(0.f, 0.f, 0.f, 0.f);
  if (valid) {
    float a0 = 0.f, a1 = 0.f, a2 = 0.f, a3 = 0.f;
    const float* w0 = W + (size_t)(4 * t + 0) * CH;
    const float* w1 = W + (size_t)(4 * t + 1) * CH;
    const float* w2 = W + (size_t)(4 * t + 2) * CH;
    const float* w3 = W + (size_t)(4 * t + 3) * CH;
    for (int k = 0; k < CH; ++k) {
      const float x = trow[k];
      a0 += x * w0[k]; a1 += x * w1[k]; a2 += x * w2[k]; a3 += x * w3[k];
    }
    v.x = a0 + bias[4 * t + 0];
    v.y = a1 + bias[4 * t + 1];
    v.z = a2 + bias[4 * t + 2];
    v.w = a3 + bias[4 * t + 3];
  }
  float s  = v.x + v.y + v.z + v.w;
  float sq = v.x * v.x + v.y * v.y + v.z * v.z + v.w * v.w;
#pragma unroll
  for (int off = 32; off > 0; off >>= 1) {
    s  += __shfl_down(s, off);
    sq += __shfl_down(sq, off);
  }
  __shared__ float red[8];
  __shared__ float stats[2];
  if ((t & 63) == 0) { red[t >> 6] = s; red[4 + (t >> 6)] = sq; }
  __syncthreads();
  if (t == 0) {
    const float S  = red[0] + red[1] + red[2] + red[3];
    const float Q  = red[4] + red[5] + red[6] + red[7];
    const float mu = S * (1.0f / CH);
    float var = Q * (1.0f / CH) - mu * mu;
    var = fmaxf(var, 0.0f);
    stats[0] = mu;
    stats[1] = rsqrtf(var + 1e-5f);
  }
  __syncthreads();
  const float mu = stats[0], rs = stats[1];
  const float4 gg = ((const float4*)g)[t];
  const float4 bb = ((const float4*)be)[t];
  float4 o;
  o.x = (v.x - mu) * rs * gg.x + bb.x;
  o.y = (v.y - mu) * rs * gg.y + bb.y;
  o.z = (v.z - mu) * rs * gg.z + bb.z;
  o.w = (v.w - mu) * rs * gg.w + bb.w;
  ((float4*)(out + ((size_t)b * TSRC + j) * CH))[t] = o;
  if (t == 0) mask_out[bx] = (float)src_mask[bx];
}

extern "C" void kernel_launch(void* const* d_in, const int* in_sizes, int n_in,
                              void* d_out, int out_size, void* d_ws, size_t ws_size,
                              hipStream_t stream) {
  (void)in_sizes; (void)n_in; (void)out_size;
  // setup_inputs order: src, src_mask, tgt, tgt_mask, conv_w, conv_b, ln_g, ln_b
  const int*   src_mask = (const int*)d_in[1];
  const float* tgt      = (const float*)d_in[2];
  const int*   tgt_mask = (const int*)d_in[3];
  const float* conv_w   = (const float*)d_in[4];
  const float* conv_b   = (const float*)d_in[5];
  const float* ln_g     = (const float*)d_in[6];
  const float* ln_b     = (const float*)d_in[7];

  float* out      = (float*)d_out;
  float* mask_out = out + (size_t)NB * TSRC * CH;   // second tuple element, as f32

  const size_t M       = (size_t)NB * TTGT;              // 16384 rows
  const size_t off_abf = 256;
  const size_t off_wbf = off_abf + M * CH * 2;           // +32 MiB
  const size_t off_y   = off_wbf + (size_t)CH * CH * 2;  // +2 MiB
  const size_t need    = off_y + M * CH * 2;             // +32 MiB => ~66 MiB

  if (ws_size >= need) {
    int*    sizes = (int*)d_ws;
    __bf16* Abf   = (__bf16*)((char*)d_ws + off_abf);
    __bf16* Wbf   = (__bf16*)((char*)d_ws + off_wbf);
    __bf16* y     = (__bf16*)((char*)d_ws + off_y);
    prep_kernel<<<NB * TTGT + CH + 16 + 128, 256, 0, stream>>>(tgt, conv_w, src_mask, tgt_mask,
                                                               Abf, Wbf, sizes, mask_out);
    gemm_kernel<<<512, 512, 0, stream>>>(Abf, Wbf, conv_b, sizes, y);
    ln_kernel<<<2048, 256, 0, stream>>>(y, sizes, ln_g, ln_b, out);
  } else {
    fallback_kernel<<<NB * TSRC, 256, 0, stream>>>(tgt, src_mask, tgt_mask, conv_w, conv_b,
                                                   ln_g, ln_b, out, mask_out);
  }
}